// Round 4
// baseline (142.562 us; speedup 1.0000x reference)
//
#include <hip/hip_runtime.h>
#include <math.h>

#define NGRAPH 1000
#define NPG    100
#define EPG    1600
#define NF     32
#define NC     10
#define KP     30
#define OUTL   16
#define INL    97
#define NITER  3
#define NT     1024

#define FSTR   100   // feat row stride (floats): 4 mod 32 banks, 16B aligned
#define HSTR   36    // hs row stride: with quad swizzle below, conflict-free
#define PSTR   164   // priors row stride (floats): 4 mod 32 banks
#define LQ     24    // 24 quads cover l=0..95; l=96 handled as scalar

#define WS_EDGES_BYTES ((size_t)NGRAPH * EPG * 4)        // 6,400,000
#define WS_CAPT_FLOATS (NC * LQ * OUTL * 4)              // 15,360
#define WS_CAPL_FLOATS (NC * OUTL)                       // 160
#define WS_CAP_BYTES   ((size_t)(WS_CAPT_FLOATS + WS_CAPL_FLOATS) * 4)

#define PIDX(i, c) ((i) * PSTR + (c) * OUTL)

struct SMem {
  float feat[NPG * FSTR];                    // 40000 : x1|x2|x3 cols 0..95, x4 col 96
  union {
    unsigned short epack[EPG];               // 3200 : (src<<8|dst), dead after CSR fill
    float priors[KP * PSTR];                 // 19680
  } u;
  union {
    float hs[NPG * HSTR];                    // 14400 : h*dinv per layer (dead after layer 4)
    struct {
      float prsq[KP * NC];                   // 1200
      float simbuf[KP * NC];                 // 1200
      float outv[NC * OUTL];                 // 640
      float smax[NC];                        // 40
      float ssum[NC];                        // 40 (stores 1/sum)
      int   order[KP];                       // 120
    } r;
  } v;
  float W[NF * NF];                          // 4096
  float bias2[2][NF];                        // 256
  unsigned char csr[EPG];                    // 1600
  int ptr[NPG + 1];                          // 404
  int cnt[NPG];                              // 400
  float dinv[NPG];                           // 400
};                                           // 81236 B -> 2 blocks/CU

__device__ __forceinline__ float4 ld4(const float* p) { return *reinterpret_cast<const float4*>(p); }
__device__ __forceinline__ void st4(float* p, float4 v) { *reinterpret_cast<float4*>(p) = v; }
__device__ __forceinline__ float dot4(float4 a, float4 b) { return a.x*b.x + a.y*b.y + a.z*b.z + a.w*b.w; }
__device__ __forceinline__ float tanh_fast(float x) {
  float e = __expf(2.f * x);                 // inf for large x -> result 1.0 (correct)
  return 1.f - 2.f / (e + 1.f);
}

// ---- pre-kernel 1: transpose edges [k][g] -> [g][k], pack local (src<<8|dst)
__global__ void prek_edges(const int* __restrict__ esrc, const int* __restrict__ edst,
                           unsigned int* __restrict__ wsE) {
  __shared__ unsigned int t[64][65];
  const int kb = blockIdx.x % (EPG / 64);    // 25
  const int gb = blockIdx.x / (EPG / 64);    // 16 (ceil(1000/64))
  const int lane = threadIdx.x & 63;
  const int row  = threadIdx.x >> 6;         // 0..3
  #pragma unroll
  for (int r = row; r < 64; r += 4) {
    int k = kb * 64 + r;
    int g = gb * 64 + lane;
    if (g < NGRAPH) {
      int idx = k * NGRAPH + g;
      int si = esrc[idx] - g * NPG;
      int di = edst[idx] - g * NPG;
      t[r][lane] = (unsigned int)((si << 8) | di);
    }
  }
  __syncthreads();
  #pragma unroll
  for (int r = row; r < 64; r += 4) {
    int g = gb * 64 + r;
    int k = kb * 64 + lane;
    if (g < NGRAPH) wsE[(size_t)g * EPG + k] = t[lane][r];
  }
}

// ---- pre-kernel 2: Wcap[c][e][l] -> capT[c][lq][e][4] (zero-padded) + capL[c][e] (l=96)
__global__ void prek_cap(const float* __restrict__ Wcap, float* __restrict__ capT,
                         float* __restrict__ capL) {
  int o = blockIdx.x * 256 + threadIdx.x;
  if (o < WS_CAPT_FLOATS) {
    int j  = o & 3;
    int e  = (o >> 2) & 15;
    int lq = (o >> 6) % LQ;
    int c  = (o >> 6) / LQ;
    capT[o] = Wcap[(c * OUTL + e) * INL + lq * 4 + j];   // lq*4+j <= 95
  }
  if (o < WS_CAPL_FLOATS) capL[o] = Wcap[o * INL + 96];
}

template <bool WSE, bool WSC>
__global__ __launch_bounds__(NT, 8) void gcn_caps(
    const float* __restrict__ x,
    const int* __restrict__ esrc, const int* __restrict__ edst,
    const float* __restrict__ W1, const float* __restrict__ b1,
    const float* __restrict__ W2, const float* __restrict__ b2,
    const float* __restrict__ W3, const float* __restrict__ b3,
    const float* __restrict__ W4, const float* __restrict__ b4,
    const float* __restrict__ Wcap,
    const unsigned int* __restrict__ wsE,
    const float* __restrict__ capT, const float* __restrict__ capL,
    float* __restrict__ out)
{
  extern __shared__ char smem_raw[];
  SMem& s = *reinterpret_cast<SMem*>(smem_raw);
  const int g = blockIdx.x;
  const int tid = threadIdx.x;

  // ---- P1: zero counters, stage W1/b1 (grid-stride: provably covers ranges)
  if (tid < NPG) s.cnt[tid] = 0;
  for (int i = tid; i < NF * NF; i += NT) s.W[i] = W1[i];
  if (tid < NF) s.bias2[0][tid] = b1[tid];
  __syncthreads();

  // ---- P2: edges -> epack + degree count
  if (WSE) {
    const unsigned int* eg = wsE + (size_t)g * EPG;
    for (int k = tid; k < EPG; k += NT) {
      unsigned int p = eg[k];
      s.u.epack[k] = (unsigned short)p;
      atomicAdd(&s.cnt[p & 0xFF], 1);
    }
  } else {
    for (int k = tid; k < EPG; k += NT) {
      int si = esrc[g + k * NGRAPH] - g * NPG;
      int di = edst[g + k * NGRAPH] - g * NPG;
      s.u.epack[k] = (unsigned short)((si << 8) | di);
      atomicAdd(&s.cnt[di], 1);
    }
  }
  __syncthreads();

  // ---- P3: wave-parallel exclusive scan (2 elems per lane)
  if (tid < 64) {
    int j = tid;
    int a0 = (2 * j < NPG) ? s.cnt[2 * j] : 0;
    int a1 = (2 * j + 1 < NPG) ? s.cnt[2 * j + 1] : 0;
    int t = a0 + a1;
    int run = t;
    #pragma unroll
    for (int off = 1; off < 64; off <<= 1) {
      int u = __shfl_up(run, off);
      if (j >= off) run += u;
    }
    int excl = run - t;
    if (2 * j < NPG) s.ptr[2 * j] = excl;
    if (2 * j + 1 < NPG) s.ptr[2 * j + 1] = excl + a0;
    if (j == 63) s.ptr[NPG] = run;
  }
  __syncthreads();
  if (tid < NPG) {
    s.dinv[tid] = rsqrtf((float)s.cnt[tid] + 1.0f);
    s.cnt[tid] = s.ptr[tid];                  // becomes fill cursor
  }
  __syncthreads();

  // ---- P4: CSR fill
  for (int k = tid; k < EPG; k += NT) {
    int pk = s.u.epack[k];
    int pos = atomicAdd(&s.cnt[pk & 0xFF], 1);
    s.csr[pos] = (unsigned char)(pk >> 8);
  }
  __syncthreads();

  // ---- P6: three 32-wide GCN layers
  const float4* xr = reinterpret_cast<const float4*>(x + (size_t)g * NPG * NF);
  for (int l = 0; l < 3; ++l) {
    // GEMM: hs[node][c] = (in[node] @ W)[c] * dinv[node]; thread = (node, c-quad)
    if (tid < NPG * 8) {
      int node = tid >> 3, cq = tid & 7;
      float4 acc = make_float4(0.f, 0.f, 0.f, 0.f);
      #pragma unroll
      for (int kq = 0; kq < 8; ++kq) {
        float4 a4 = (l == 0) ? xr[node * 8 + kq]
                             : ld4(&s.feat[node * FSTR + (l - 1) * NF + kq * 4]);
        const float av[4] = {a4.x, a4.y, a4.z, a4.w};
        #pragma unroll
        for (int j = 0; j < 4; ++j) {
          float4 w4 = ld4(&s.W[(kq * 4 + j) * NF + cq * 4]);
          acc.x += av[j] * w4.x; acc.y += av[j] * w4.y;
          acc.z += av[j] * w4.z; acc.w += av[j] * w4.w;
        }
      }
      float di = s.dinv[node];
      acc.x *= di; acc.y *= di; acc.z *= di; acc.w *= di;
      st4(&s.v.hs[node * HSTR + ((cq ^ (node >> 3)) & 7) * 4], acc);
    }
    __syncthreads();

    // prefetch next weights (grid-stride over all threads; AGG never reads W)
    if (l == 0) {
      for (int i = tid; i < NF * NF; i += NT) s.W[i] = W2[i];
      if (tid < NF) s.bias2[1][tid] = b2[tid];
    } else if (l == 1) {
      for (int i = tid; i < NF * NF; i += NT) s.W[i] = W3[i];
      if (tid < NF) s.bias2[0][tid] = b3[tid];
    } else {
      if (tid < NF) s.W[tid] = W4[tid];
      if (tid == NT - 1) s.bias2[1][0] = b4[0];
    }

    // AGG: feat[d][l*32+f] = tanh(dinv[d]*(sum_e hs[src] + hs[d]) + b); thread = (d, f-quad)
    if (tid < NPG * 8) {
      int d = tid >> 3, fq = tid & 7;
      const float* bc = s.bias2[l & 1];
      float4 b4q = ld4(&bc[fq * 4]);
      float4 r = ld4(&s.v.hs[d * HSTR + ((fq ^ (d >> 3)) & 7) * 4]);  // self term
      int p0 = s.ptr[d], p1 = s.ptr[d + 1];
      int idx = p0;
      for (; idx + 1 < p1; idx += 2) {
        int sc0 = s.csr[idx], sc1 = s.csr[idx + 1];
        float4 h0 = ld4(&s.v.hs[sc0 * HSTR + ((fq ^ (sc0 >> 3)) & 7) * 4]);
        float4 h1 = ld4(&s.v.hs[sc1 * HSTR + ((fq ^ (sc1 >> 3)) & 7) * 4]);
        r.x += h0.x + h1.x; r.y += h0.y + h1.y;
        r.z += h0.z + h1.z; r.w += h0.w + h1.w;
      }
      if (idx < p1) {
        int sc = s.csr[idx];
        float4 hq = ld4(&s.v.hs[sc * HSTR + ((fq ^ (sc >> 3)) & 7) * 4]);
        r.x += hq.x; r.y += hq.y; r.z += hq.z; r.w += hq.w;
      }
      float di = s.dinv[d];
      float4 o;
      o.x = tanh_fast(di * r.x + b4q.x);
      o.y = tanh_fast(di * r.y + b4q.y);
      o.z = tanh_fast(di * r.z + b4q.z);
      o.w = tanh_fast(di * r.w + b4q.w);
      st4(&s.feat[d * FSTR + l * NF + fq * 4], o);
    }
    __syncthreads();
  }

  // ---- layer 4 (1-wide output)
  float* hsf = s.v.hs;  // flat reuse, 100 floats
  if (tid < NPG) {
    float a = 0.f;
    #pragma unroll
    for (int kq = 0; kq < 8; ++kq) {
      float4 a4 = ld4(&s.feat[tid * FSTR + 64 + kq * 4]);
      float4 w4 = ld4(&s.W[kq * 4]);
      a += dot4(a4, w4);
    }
    hsf[tid] = a * s.dinv[tid];
  }
  __syncthreads();
  if (tid < NPG) {
    float r = hsf[tid];
    int p0 = s.ptr[tid], p1 = s.ptr[tid + 1];
    for (int idx = p0; idx < p1; ++idx) r += hsf[s.csr[idx]];
    s.feat[tid * FSTR + 96] = tanh_fast(s.dinv[tid] * r + s.bias2[1][0]);
  }
  __syncthreads();

  // ---- P7: stable top-30 by col 96 desc; 8 threads per node, shfl-combined
  if (tid < NPG * 8) {
    int i = tid >> 3, p = tid & 7;
    float vv = s.feat[i * FSTR + 96];
    int j0 = p * 13, j1 = min(NPG, j0 + 13);
    int rank = 0;
    for (int j = j0; j < j1; ++j) {
      float vj = s.feat[j * FSTR + 96];
      rank += (vj > vv) || (vj == vv && j < i);
    }
    rank += __shfl_xor(rank, 1);
    rank += __shfl_xor(rank, 2);
    rank += __shfl_xor(rank, 4);
    if (p == 0 && rank < KP) s.v.r.order[rank] = i;
  }
  __syncthreads();

  // ---- P8: priors[i][c][e] = pooled[i] . Wcap[c][e]; thread = (i,e)
  if (tid < KP * OUTL) {
    int i = tid >> 4, e = tid & 15;
    int row = s.v.r.order[i] * FSTR;
    float acc[NC];
    #pragma unroll
    for (int c = 0; c < NC; ++c) acc[c] = 0.f;
    if (WSC) {
      for (int lq = 0; lq < LQ; ++lq) {
        float4 f4 = ld4(&s.feat[row + lq * 4]);
        #pragma unroll
        for (int c = 0; c < NC; ++c) {
          float4 w4 = ld4(capT + ((c * LQ + lq) * OUTL + e) * 4);
          acc[c] += dot4(f4, w4);
        }
      }
      float xl = s.feat[row + 96];
      #pragma unroll
      for (int c = 0; c < NC; ++c) acc[c] += xl * capL[c * OUTL + e];
    } else {
      for (int c = 0; c < NC; ++c) {
        float a = 0.f;
        for (int l = 0; l < INL; ++l) a += s.feat[row + l] * Wcap[(c * OUTL + e) * INL + l];
        acc[c] = a;
      }
    }
    #pragma unroll
    for (int c = 0; c < NC; ++c) s.u.priors[PIDX(i, c) + e] = acc[c];
  }
  __syncthreads();

  // ---- P9: pr_sq, out init
  if (tid < KP * NC) {
    int i = tid / NC, c = tid % NC;
    const float* pr = &s.u.priors[PIDX(i, c)];
    float a = 0.f;
    #pragma unroll
    for (int eq = 0; eq < 4; ++eq) { float4 p = ld4(pr + eq * 4); a += dot4(p, p); }
    s.v.r.prsq[tid] = a;
  }
  if (tid < NC * OUTL) {
    int c = tid >> 4, e = tid & 15;
    float a = 0.f;
    #pragma unroll
    for (int i = 0; i < KP; ++i) a += s.u.priors[PIDX(i, c) + e];
    s.v.r.outv[tid] = a * (1.0f / KP);
  }
  __syncthreads();

  // ---- P10: routing (3 barriers per iter)
  for (int it = 0; it < NITER; ++it) {
    if (tid < KP * NC) {
      int i = tid / NC, c = tid % NC;
      const float* pr = &s.u.priors[PIDX(i, c)];
      const float* ov = &s.v.r.outv[c * OUTL];
      float xy = 0.f, oq = 0.f;
      #pragma unroll
      for (int eq = 0; eq < 4; ++eq) {
        float4 p = ld4(pr + eq * 4);
        float4 o = ld4(ov + eq * 4);
        xy += dot4(p, o); oq += dot4(o, o);
      }
      s.v.r.simbuf[tid] = xy / (s.v.r.prsq[tid] + oq - xy);
    }
    __syncthreads();
    if (tid < NC) {
      float m = -1e30f;
      #pragma unroll
      for (int i = 0; i < KP; ++i) m = fmaxf(m, s.v.r.simbuf[i * NC + tid]);
      float ss = 0.f;
      #pragma unroll
      for (int i = 0; i < KP; ++i) ss += __expf(s.v.r.simbuf[i * NC + tid] - m);
      s.v.r.smax[tid] = m;
      s.v.r.ssum[tid] = 1.f / ss;
    }
    __syncthreads();
    if (tid < NC * OUTL) {
      int c = tid >> 4, e = tid & 15;
      float m = s.v.r.smax[c], is = s.v.r.ssum[c], a = 0.f;
      #pragma unroll
      for (int i = 0; i < KP; ++i)
        a += __expf(s.v.r.simbuf[i * NC + c] - m) * s.u.priors[PIDX(i, c) + e];
      s.v.r.outv[tid] = a * is;
    }
    __syncthreads();
  }

  // ---- P11: classes = ||out||
  if (tid < NC) {
    const float* ov = &s.v.r.outv[tid * OUTL];
    float a = 0.f;
    #pragma unroll
    for (int eq = 0; eq < 4; ++eq) { float4 o = ld4(ov + eq * 4); a += dot4(o, o); }
    out[(size_t)g * NC + tid] = sqrtf(a);
  }
}

extern "C" void kernel_launch(void* const* d_in, const int* in_sizes, int n_in,
                              void* d_out, int out_size, void* d_ws, size_t ws_size,
                              hipStream_t stream) {
  const float* x    = (const float*)d_in[0];
  const int*   esrc = (const int*)d_in[1];
  const int*   edst = (const int*)d_in[2];
  const float* W1 = (const float*)d_in[4];
  const float* b1 = (const float*)d_in[5];
  const float* W2 = (const float*)d_in[6];
  const float* b2 = (const float*)d_in[7];
  const float* W3 = (const float*)d_in[8];
  const float* b3 = (const float*)d_in[9];
  const float* W4 = (const float*)d_in[10];
  const float* b4 = (const float*)d_in[11];
  const float* Wcap = (const float*)d_in[12];
  float* outp = (float*)d_out;

  const bool wse = ws_size >= WS_EDGES_BYTES + WS_CAP_BYTES;
  const bool wsc = ws_size >= WS_CAP_BYTES;

  unsigned int* wsE = (unsigned int*)d_ws;
  float* capT = wse ? (float*)((char*)d_ws + WS_EDGES_BYTES) : (float*)d_ws;
  float* capL = capT + WS_CAPT_FLOATS;

  (void)hipFuncSetAttribute((const void*)gcn_caps<true, true>,
                            hipFuncAttributeMaxDynamicSharedMemorySize, (int)sizeof(SMem));
  (void)hipFuncSetAttribute((const void*)gcn_caps<false, true>,
                            hipFuncAttributeMaxDynamicSharedMemorySize, (int)sizeof(SMem));
  (void)hipFuncSetAttribute((const void*)gcn_caps<false, false>,
                            hipFuncAttributeMaxDynamicSharedMemorySize, (int)sizeof(SMem));

  if (wse) {
    prek_edges<<<(EPG / 64) * 16, 256, 0, stream>>>(esrc, edst, wsE);
    prek_cap<<<(WS_CAPT_FLOATS + 255) / 256, 256, 0, stream>>>(Wcap, capT, capL);
    gcn_caps<true, true><<<NGRAPH, NT, sizeof(SMem), stream>>>(
        x, esrc, edst, W1, b1, W2, b2, W3, b3, W4, b4, Wcap, wsE, capT, capL, outp);
  } else if (wsc) {
    prek_cap<<<(WS_CAPT_FLOATS + 255) / 256, 256, 0, stream>>>(Wcap, capT, capL);
    gcn_caps<false, true><<<NGRAPH, NT, sizeof(SMem), stream>>>(
        x, esrc, edst, W1, b1, W2, b2, W3, b3, W4, b4, Wcap, wsE, capT, capL, outp);
  } else {
    gcn_caps<false, false><<<NGRAPH, NT, sizeof(SMem), stream>>>(
        x, esrc, edst, W1, b1, W2, b2, W3, b3, W4, b4, Wcap, wsE, capT, capL, outp);
  }
}

// Round 5
// 137.799 us; speedup vs baseline: 1.0346x; 1.0346x over previous
//
#include <hip/hip_runtime.h>
#include <math.h>

#define NGRAPH 1000
#define NPG    100
#define EPG    1600
#define NF     32
#define NC     10
#define KP     30
#define OUTL   16
#define INL    97
#define NITER  3

#define NTV    512    // v5 (split-LDS) block size
#define NTF    1024   // fused fallback block size

#define XSTR   36     // xbuf/hs row stride (floats): 16B-aligned, (9r+q)%8=(r+q)%8 rotation
#define FSTR   100    // fused: feat row stride
#define HSTR   36     // fused: hs row stride
#define PSTR   164    // priors row stride (floats): 4 mod 32 banks
#define LQ     24     // 24 quads cover l=0..95; l=96 scalar

#define WS_EDGES_BYTES ((size_t)NGRAPH * EPG * 4)            // 6,400,000
#define WS_CAPT_FLOATS (NC * LQ * OUTL * 4)                  // 15,360
#define WS_CAPL_FLOATS (NC * OUTL)                           // 160
#define WS_CAP_BYTES   ((size_t)(WS_CAPT_FLOATS + WS_CAPL_FLOATS) * 4)
#define WS_FEATG_OFF   (WS_EDGES_BYTES + WS_CAP_BYTES)       // 6,462,080 (16B aligned)
#define WS_FEATG_BYTES ((size_t)NGRAPH * NPG * 100 * 4)      // 40,000,000
#define WS_FULL_BYTES  (WS_FEATG_OFF + WS_FEATG_BYTES)       // 46,462,080

#define PIDX(i, c) ((i) * PSTR + (c) * OUTL)

__device__ __forceinline__ float4 ld4(const float* p) { return *reinterpret_cast<const float4*>(p); }
__device__ __forceinline__ void st4(float* p, float4 v) { *reinterpret_cast<float4*>(p) = v; }
__device__ __forceinline__ float dot4(float4 a, float4 b) { return a.x*b.x + a.y*b.y + a.z*b.z + a.w*b.w; }
__device__ __forceinline__ float tanh_fast(float x) {
  float e = __expf(2.f * x);                 // inf for large x -> result 1.0 (correct)
  return 1.f - 2.f / (e + 1.f);
}

// ---- pre-kernel 1: transpose edges [k][g] -> [g][k], pack local (src<<8|dst)
__global__ void prek_edges(const int* __restrict__ esrc, const int* __restrict__ edst,
                           unsigned int* __restrict__ wsE) {
  __shared__ unsigned int t[64][65];
  const int kb = blockIdx.x % (EPG / 64);    // 25
  const int gb = blockIdx.x / (EPG / 64);    // 16
  const int lane = threadIdx.x & 63;
  const int row  = threadIdx.x >> 6;         // 0..3
  #pragma unroll
  for (int r = row; r < 64; r += 4) {
    int k = kb * 64 + r;
    int g = gb * 64 + lane;
    if (g < NGRAPH) {
      int idx = k * NGRAPH + g;
      int si = esrc[idx] - g * NPG;
      int di = edst[idx] - g * NPG;
      t[r][lane] = (unsigned int)((si << 8) | di);
    }
  }
  __syncthreads();
  #pragma unroll
  for (int r = row; r < 64; r += 4) {
    int g = gb * 64 + r;
    int k = kb * 64 + lane;
    if (g < NGRAPH) wsE[(size_t)g * EPG + k] = t[lane][r];
  }
}

// ---- pre-kernel 2: Wcap[c][e][l] -> capT[c][lq][e][4] + capL[c][e] (l=96)
__global__ void prek_cap(const float* __restrict__ Wcap, float* __restrict__ capT,
                         float* __restrict__ capL) {
  int o = blockIdx.x * 256 + threadIdx.x;
  if (o < WS_CAPT_FLOATS) {
    int j  = o & 3;
    int e  = (o >> 2) & 15;
    int lq = (o >> 6) % LQ;
    int c  = (o >> 6) / LQ;
    capT[o] = Wcap[(c * OUTL + e) * INL + lq * 4 + j];
  }
  if (o < WS_CAPL_FLOATS) capL[o] = Wcap[o * INL + 96];
}

// ============================ v5: 38KB LDS, 4 blocks/CU ============================
struct SMemV5 {
  union {
    struct {                         // phase A: CSR build + GCN layers + selection
      float xbuf[NPG * XSTR];        // 14400 : current layer input (in-place updated)
      float hs[NPG * XSTR];          // 14400 : h*dinv
      float W[NF * NF];              // 4096
      float bias2[2][NF];            // 256
      unsigned short csr16[EPG];     // 3200 : src*XSTR float-offsets, grouped by dst
      int cnt[NPG];                  // 400
      float dinv[NPG];               // 400
      float col96[NPG];              // 400 : f32 exact selection key
      int ptr[NPG + 1];              // 404
    } a;                             // 37956 B
    struct {                         // phase B: priors + routing
      float feat30[KP * 100];        // 12000
      float priors[KP * PSTR];       // 19680
      float prsq[KP * NC];           // 1200
      float simbuf[KP * NC];         // 1200
      float outv[NC * OUTL];         // 640
    } b;                             // 34720 B
  } u;
  int order[KP];                     // 120
};                                   // ~38.1 KB -> 4 blocks/CU

__global__ __launch_bounds__(NTV, 8) void gcn_caps_v5(
    const float* __restrict__ x,
    const unsigned int* __restrict__ wsE,
    const float* __restrict__ W1, const float* __restrict__ b1,
    const float* __restrict__ W2, const float* __restrict__ b2,
    const float* __restrict__ W3, const float* __restrict__ b3,
    const float* __restrict__ W4, const float* __restrict__ b4,
    const float* __restrict__ capT, const float* __restrict__ capL,
    float* __restrict__ featG,
    float* __restrict__ out)
{
  extern __shared__ char smraw[];
  SMemV5& s = *reinterpret_cast<SMemV5*>(smraw);
  const int g = blockIdx.x;
  const int tid = threadIdx.x;

  // A1: zero counters, stage W1/b1, stage x into xbuf (stride 36)
  if (tid < NPG) s.u.a.cnt[tid] = 0;
  for (int i = tid; i < NF * NF; i += NTV) s.u.a.W[i] = W1[i];
  if (tid < NF) s.u.a.bias2[0][tid] = b1[tid];
  const float4* xr = reinterpret_cast<const float4*>(x + (size_t)g * NPG * NF);
  for (int o = tid; o < NPG * 8; o += NTV) {
    int node = o >> 3, kq = o & 7;
    st4(&s.u.a.xbuf[node * XSTR + kq * 4], xr[o]);
  }
  __syncthreads();

  // A2: degree count (coalesced wsE read)
  const unsigned int* eg = wsE + (size_t)g * EPG;
  for (int k = tid; k < EPG; k += NTV) atomicAdd(&s.u.a.cnt[eg[k] & 0xFF], 1);
  __syncthreads();

  // A3: wave-parallel exclusive scan (2 elems/lane), dinv, cursors
  if (tid < 64) {
    int j = tid;
    int a0 = (2 * j < NPG) ? s.u.a.cnt[2 * j] : 0;
    int a1 = (2 * j + 1 < NPG) ? s.u.a.cnt[2 * j + 1] : 0;
    int t = a0 + a1;
    int run = t;
    #pragma unroll
    for (int off = 1; off < 64; off <<= 1) {
      int u = __shfl_up(run, off);
      if (j >= off) run += u;
    }
    int excl = run - t;
    if (2 * j < NPG) s.u.a.ptr[2 * j] = excl;
    if (2 * j + 1 < NPG) s.u.a.ptr[2 * j + 1] = excl + a0;
    if (j == 63) s.u.a.ptr[NPG] = run;
  }
  __syncthreads();
  if (tid < NPG) {
    s.u.a.dinv[tid] = rsqrtf((float)s.u.a.cnt[tid] + 1.0f);
    s.u.a.cnt[tid] = s.u.a.ptr[tid];
  }
  __syncthreads();

  // A4: CSR fill — store src*XSTR so AGG loads need zero address math
  for (int k = tid; k < EPG; k += NTV) {
    unsigned int p = eg[k];
    int pos = atomicAdd(&s.u.a.cnt[p & 0xFF], 1);
    s.u.a.csr16[pos] = (unsigned short)(((p >> 8) & 0xFF) * XSTR);
  }
  __syncthreads();

  float* fG = featG + (size_t)g * NPG * 100;

  // A5: three 32-wide GCN layers, xbuf updated in place, cols streamed to featG
  for (int l = 0; l < 3; ++l) {
    for (int o = tid; o < NPG * 8; o += NTV) {       // GEMM
      int node = o >> 3, cq = o & 7;
      float4 acc = make_float4(0.f, 0.f, 0.f, 0.f);
      #pragma unroll
      for (int kq = 0; kq < 8; ++kq) {
        float4 a4 = ld4(&s.u.a.xbuf[node * XSTR + kq * 4]);
        const float av[4] = {a4.x, a4.y, a4.z, a4.w};
        #pragma unroll
        for (int j = 0; j < 4; ++j) {
          float4 w4 = ld4(&s.u.a.W[(kq * 4 + j) * NF + cq * 4]);
          acc.x += av[j] * w4.x; acc.y += av[j] * w4.y;
          acc.z += av[j] * w4.z; acc.w += av[j] * w4.w;
        }
      }
      float di = s.u.a.dinv[node];
      acc.x *= di; acc.y *= di; acc.z *= di; acc.w *= di;
      st4(&s.u.a.hs[node * XSTR + cq * 4], acc);
    }
    __syncthreads();

    // prefetch next weights (overlaps AGG; AGG never reads W)
    if (l == 0) {
      for (int i = tid; i < NF * NF; i += NTV) s.u.a.W[i] = W2[i];
      if (tid < NF) s.u.a.bias2[1][tid] = b2[tid];
    } else if (l == 1) {
      for (int i = tid; i < NF * NF; i += NTV) s.u.a.W[i] = W3[i];
      if (tid < NF) s.u.a.bias2[0][tid] = b3[tid];
    } else {
      if (tid < NF) s.u.a.W[tid] = W4[tid];
      if (tid == NTV - 1) s.u.a.bias2[1][0] = b4[0];
    }

    for (int o = tid; o < NPG * 8; o += NTV) {       // AGG
      int d = o >> 3, fq4 = (o & 7) * 4;
      const float* bc = s.u.a.bias2[l & 1];
      float4 bq = ld4(&bc[fq4]);
      float4 r = ld4(&s.u.a.hs[d * XSTR + fq4]);     // self term
      int p0 = s.u.a.ptr[d], p1 = s.u.a.ptr[d + 1];
      int idx = p0;
      for (; idx + 4 <= p1; idx += 4) {
        int o0 = s.u.a.csr16[idx],     o1 = s.u.a.csr16[idx + 1];
        int o2 = s.u.a.csr16[idx + 2], o3 = s.u.a.csr16[idx + 3];
        float4 h0 = ld4(&s.u.a.hs[o0 + fq4]);
        float4 h1 = ld4(&s.u.a.hs[o1 + fq4]);
        float4 h2 = ld4(&s.u.a.hs[o2 + fq4]);
        float4 h3 = ld4(&s.u.a.hs[o3 + fq4]);
        r.x += (h0.x + h1.x) + (h2.x + h3.x);
        r.y += (h0.y + h1.y) + (h2.y + h3.y);
        r.z += (h0.z + h1.z) + (h2.z + h3.z);
        r.w += (h0.w + h1.w) + (h2.w + h3.w);
      }
      for (; idx < p1; ++idx) {
        float4 h = ld4(&s.u.a.hs[s.u.a.csr16[idx] + fq4]);
        r.x += h.x; r.y += h.y; r.z += h.z; r.w += h.w;
      }
      float di = s.u.a.dinv[d];
      float4 oo;
      oo.x = tanh_fast(di * r.x + bq.x);
      oo.y = tanh_fast(di * r.y + bq.y);
      oo.z = tanh_fast(di * r.z + bq.z);
      oo.w = tanh_fast(di * r.w + bq.w);
      st4(&s.u.a.xbuf[d * XSTR + fq4], oo);          // in-place: next layer input
      st4(&fG[d * 100 + l * NF + fq4], oo);          // stream to global
    }
    __syncthreads();
  }

  // A6: layer 4 (1-wide) -> col96 (f32 exact) + featG
  if (tid < NPG) {
    float a = 0.f;
    #pragma unroll
    for (int kq = 0; kq < 8; ++kq)
      a += dot4(ld4(&s.u.a.xbuf[tid * XSTR + kq * 4]), ld4(&s.u.a.W[kq * 4]));
    s.u.a.hs[tid * XSTR] = a * s.u.a.dinv[tid];
  }
  __syncthreads();
  if (tid < NPG) {
    float r = s.u.a.hs[tid * XSTR];
    int p0 = s.u.a.ptr[tid], p1 = s.u.a.ptr[tid + 1];
    for (int idx = p0; idx < p1; ++idx) r += s.u.a.hs[s.u.a.csr16[idx]];
    float c96 = tanh_fast(s.u.a.dinv[tid] * r + s.u.a.bias2[1][0]);
    s.u.a.col96[tid] = c96;
    fG[tid * 100 + 96] = c96;
  }
  __syncthreads();

  // A7: stable top-30 by col96 desc; 4 threads/node, shfl-combined
  if (tid < NPG * 4) {
    int i = tid >> 2, p = tid & 3;
    float vv = s.u.a.col96[i];
    int j0 = p * 25, j1 = j0 + 25;
    int rank = 0;
    for (int j = j0; j < j1; ++j) {
      float vj = s.u.a.col96[j];
      rank += (vj > vv) || (vj == vv && j < i);
    }
    rank += __shfl_xor(rank, 1);
    rank += __shfl_xor(rank, 2);
    if (p == 0 && rank < KP) s.order[rank] = i;
  }
  __syncthreads();

  // B1: gather the 30 selected rows back from featG (L2-hot; cols 97..99 unused)
  for (int idx = tid; idx < KP * 100; idx += NTV) {
    int r = idx / 100, c = idx - r * 100;
    s.u.b.feat30[idx] = featG[((size_t)g * NPG + s.order[r]) * 100 + c];
  }
  __syncthreads();

  // B2: priors[i][c][e] = pooled[i] . Wcap[c][e]
  if (tid < KP * OUTL) {
    int i = tid >> 4, e = tid & 15;
    const float* fr = &s.u.b.feat30[i * 100];
    float acc[NC];
    #pragma unroll
    for (int c = 0; c < NC; ++c) acc[c] = 0.f;
    for (int lq = 0; lq < LQ; ++lq) {
      float4 f4 = ld4(fr + lq * 4);
      #pragma unroll
      for (int c = 0; c < NC; ++c) {
        float4 w4 = ld4(capT + ((c * LQ + lq) * OUTL + e) * 4);
        acc[c] += dot4(f4, w4);
      }
    }
    float xl = fr[96];
    #pragma unroll
    for (int c = 0; c < NC; ++c) acc[c] += xl * capL[c * OUTL + e];
    #pragma unroll
    for (int c = 0; c < NC; ++c) s.u.b.priors[PIDX(i, c) + e] = acc[c];
  }
  __syncthreads();

  // B3: pr_sq + out init
  if (tid < KP * NC) {
    int i = tid / NC, c = tid % NC;
    const float* pr = &s.u.b.priors[PIDX(i, c)];
    float a = 0.f;
    #pragma unroll
    for (int eq = 0; eq < 4; ++eq) { float4 p = ld4(pr + eq * 4); a += dot4(p, p); }
    s.u.b.prsq[tid] = a;
  }
  if (tid < NC * OUTL) {
    int c = tid >> 4, e = tid & 15;
    float a = 0.f;
    #pragma unroll
    for (int i = 0; i < KP; ++i) a += s.u.b.priors[PIDX(i, c) + e];
    s.u.b.outv[tid] = a * (1.0f / KP);
  }
  __syncthreads();

  // B4: routing, 2 barriers/iter (softmax merged into update)
  for (int it = 0; it < NITER; ++it) {
    if (tid < KP * NC) {
      int i = tid / NC, c = tid % NC;
      const float* pr = &s.u.b.priors[PIDX(i, c)];
      const float* ov = &s.u.b.outv[c * OUTL];
      float xy = 0.f, oq = 0.f;
      #pragma unroll
      for (int eq = 0; eq < 4; ++eq) {
        float4 p = ld4(pr + eq * 4);
        float4 o = ld4(ov + eq * 4);
        xy += dot4(p, o); oq += dot4(o, o);
      }
      s.u.b.simbuf[tid] = xy / (s.u.b.prsq[tid] + oq - xy);
    }
    __syncthreads();
    if (tid < NC * OUTL) {
      int c = tid >> 4, e = tid & 15;
      float m = -1e30f;
      #pragma unroll
      for (int i = 0; i < KP; ++i) m = fmaxf(m, s.u.b.simbuf[i * NC + c]);
      float ss = 0.f, a = 0.f;
      #pragma unroll
      for (int i = 0; i < KP; ++i) {
        float w = __expf(s.u.b.simbuf[i * NC + c] - m);
        ss += w;
        a += w * s.u.b.priors[PIDX(i, c) + e];
      }
      s.u.b.outv[tid] = a / ss;
    }
    __syncthreads();
  }

  // B5: classes = ||out||
  if (tid < NC) {
    const float* ov = &s.u.b.outv[tid * OUTL];
    float a = 0.f;
    #pragma unroll
    for (int eq = 0; eq < 4; ++eq) { float4 o = ld4(ov + eq * 4); a += dot4(o, o); }
    out[(size_t)g * NC + tid] = sqrtf(a);
  }
}

// ==================== fused fallback (proven R4 kernel, 81KB LDS) ====================
struct SMemF {
  float feat[NPG * FSTR];
  union {
    unsigned short epack[EPG];
    float priors[KP * PSTR];
  } u;
  union {
    float hs[NPG * HSTR];
    struct {
      float prsq[KP * NC];
      float simbuf[KP * NC];
      float outv[NC * OUTL];
      float smax[NC];
      float ssum[NC];
      int   order[KP];
    } r;
  } v;
  float W[NF * NF];
  float bias2[2][NF];
  unsigned char csr[EPG];
  int ptr[NPG + 1];
  int cnt[NPG];
  float dinv[NPG];
};

template <bool WSE, bool WSC>
__global__ __launch_bounds__(NTF, 8) void gcn_caps_fused(
    const float* __restrict__ x,
    const int* __restrict__ esrc, const int* __restrict__ edst,
    const float* __restrict__ W1, const float* __restrict__ b1,
    const float* __restrict__ W2, const float* __restrict__ b2,
    const float* __restrict__ W3, const float* __restrict__ b3,
    const float* __restrict__ W4, const float* __restrict__ b4,
    const float* __restrict__ Wcap,
    const unsigned int* __restrict__ wsE,
    const float* __restrict__ capT, const float* __restrict__ capL,
    float* __restrict__ out)
{
  extern __shared__ char smem_raw[];
  SMemF& s = *reinterpret_cast<SMemF*>(smem_raw);
  const int g = blockIdx.x;
  const int tid = threadIdx.x;

  if (tid < NPG) s.cnt[tid] = 0;
  for (int i = tid; i < NF * NF; i += NTF) s.W[i] = W1[i];
  if (tid < NF) s.bias2[0][tid] = b1[tid];
  __syncthreads();

  if (WSE) {
    const unsigned int* eg = wsE + (size_t)g * EPG;
    for (int k = tid; k < EPG; k += NTF) {
      unsigned int p = eg[k];
      s.u.epack[k] = (unsigned short)p;
      atomicAdd(&s.cnt[p & 0xFF], 1);
    }
  } else {
    for (int k = tid; k < EPG; k += NTF) {
      int si = esrc[g + k * NGRAPH] - g * NPG;
      int di = edst[g + k * NGRAPH] - g * NPG;
      s.u.epack[k] = (unsigned short)((si << 8) | di);
      atomicAdd(&s.cnt[di], 1);
    }
  }
  __syncthreads();

  if (tid < 64) {
    int j = tid;
    int a0 = (2 * j < NPG) ? s.cnt[2 * j] : 0;
    int a1 = (2 * j + 1 < NPG) ? s.cnt[2 * j + 1] : 0;
    int t = a0 + a1;
    int run = t;
    #pragma unroll
    for (int off = 1; off < 64; off <<= 1) {
      int u = __shfl_up(run, off);
      if (j >= off) run += u;
    }
    int excl = run - t;
    if (2 * j < NPG) s.ptr[2 * j] = excl;
    if (2 * j + 1 < NPG) s.ptr[2 * j + 1] = excl + a0;
    if (j == 63) s.ptr[NPG] = run;
  }
  __syncthreads();
  if (tid < NPG) {
    s.dinv[tid] = rsqrtf((float)s.cnt[tid] + 1.0f);
    s.cnt[tid] = s.ptr[tid];
  }
  __syncthreads();

  for (int k = tid; k < EPG; k += NTF) {
    int pk = s.u.epack[k];
    int pos = atomicAdd(&s.cnt[pk & 0xFF], 1);
    s.csr[pos] = (unsigned char)(pk >> 8);
  }
  __syncthreads();

  const float4* xr = reinterpret_cast<const float4*>(x + (size_t)g * NPG * NF);
  for (int l = 0; l < 3; ++l) {
    if (tid < NPG * 8) {
      int node = tid >> 3, cq = tid & 7;
      float4 acc = make_float4(0.f, 0.f, 0.f, 0.f);
      #pragma unroll
      for (int kq = 0; kq < 8; ++kq) {
        float4 a4 = (l == 0) ? xr[node * 8 + kq]
                             : ld4(&s.feat[node * FSTR + (l - 1) * NF + kq * 4]);
        const float av[4] = {a4.x, a4.y, a4.z, a4.w};
        #pragma unroll
        for (int j = 0; j < 4; ++j) {
          float4 w4 = ld4(&s.W[(kq * 4 + j) * NF + cq * 4]);
          acc.x += av[j] * w4.x; acc.y += av[j] * w4.y;
          acc.z += av[j] * w4.z; acc.w += av[j] * w4.w;
        }
      }
      float di = s.dinv[node];
      acc.x *= di; acc.y *= di; acc.z *= di; acc.w *= di;
      st4(&s.v.hs[node * HSTR + ((cq ^ (node >> 3)) & 7) * 4], acc);
    }
    __syncthreads();

    if (l == 0) {
      for (int i = tid; i < NF * NF; i += NTF) s.W[i] = W2[i];
      if (tid < NF) s.bias2[1][tid] = b2[tid];
    } else if (l == 1) {
      for (int i = tid; i < NF * NF; i += NTF) s.W[i] = W3[i];
      if (tid < NF) s.bias2[0][tid] = b3[tid];
    } else {
      if (tid < NF) s.W[tid] = W4[tid];
      if (tid == NTF - 1) s.bias2[1][0] = b4[0];
    }

    if (tid < NPG * 8) {
      int d = tid >> 3, fq = tid & 7;
      const float* bc = s.bias2[l & 1];
      float4 b4q = ld4(&bc[fq * 4]);
      float4 r = ld4(&s.v.hs[d * HSTR + ((fq ^ (d >> 3)) & 7) * 4]);
      int p0 = s.ptr[d], p1 = s.ptr[d + 1];
      int idx = p0;
      for (; idx + 1 < p1; idx += 2) {
        int sc0 = s.csr[idx], sc1 = s.csr[idx + 1];
        float4 h0 = ld4(&s.v.hs[sc0 * HSTR + ((fq ^ (sc0 >> 3)) & 7) * 4]);
        float4 h1 = ld4(&s.v.hs[sc1 * HSTR + ((fq ^ (sc1 >> 3)) & 7) * 4]);
        r.x += h0.x + h1.x; r.y += h0.y + h1.y;
        r.z += h0.z + h1.z; r.w += h0.w + h1.w;
      }
      if (idx < p1) {
        int sc = s.csr[idx];
        float4 hq = ld4(&s.v.hs[sc * HSTR + ((fq ^ (sc >> 3)) & 7) * 4]);
        r.x += hq.x; r.y += hq.y; r.z += hq.z; r.w += hq.w;
      }
      float di = s.dinv[d];
      float4 o;
      o.x = tanh_fast(di * r.x + b4q.x);
      o.y = tanh_fast(di * r.y + b4q.y);
      o.z = tanh_fast(di * r.z + b4q.z);
      o.w = tanh_fast(di * r.w + b4q.w);
      st4(&s.feat[d * FSTR + l * NF + fq * 4], o);
    }
    __syncthreads();
  }

  float* hsf = s.v.hs;
  if (tid < NPG) {
    float a = 0.f;
    #pragma unroll
    for (int kq = 0; kq < 8; ++kq)
      a += dot4(ld4(&s.feat[tid * FSTR + 64 + kq * 4]), ld4(&s.W[kq * 4]));
    hsf[tid] = a * s.dinv[tid];
  }
  __syncthreads();
  if (tid < NPG) {
    float r = hsf[tid];
    int p0 = s.ptr[tid], p1 = s.ptr[tid + 1];
    for (int idx = p0; idx < p1; ++idx) r += hsf[s.csr[idx]];
    s.feat[tid * FSTR + 96] = tanh_fast(s.dinv[tid] * r + s.bias2[1][0]);
  }
  __syncthreads();

  if (tid < NPG * 8) {
    int i = tid >> 3, p = tid & 7;
    float vv = s.feat[i * FSTR + 96];
    int j0 = p * 13, j1 = min(NPG, j0 + 13);
    int rank = 0;
    for (int j = j0; j < j1; ++j) {
      float vj = s.feat[j * FSTR + 96];
      rank += (vj > vv) || (vj == vv && j < i);
    }
    rank += __shfl_xor(rank, 1);
    rank += __shfl_xor(rank, 2);
    rank += __shfl_xor(rank, 4);
    if (p == 0 && rank < KP) s.v.r.order[rank] = i;
  }
  __syncthreads();

  if (tid < KP * OUTL) {
    int i = tid >> 4, e = tid & 15;
    int row = s.v.r.order[i] * FSTR;
    float acc[NC];
    #pragma unroll
    for (int c = 0; c < NC; ++c) acc[c] = 0.f;
    if (WSC) {
      for (int lq = 0; lq < LQ; ++lq) {
        float4 f4 = ld4(&s.feat[row + lq * 4]);
        #pragma unroll
        for (int c = 0; c < NC; ++c) {
          float4 w4 = ld4(capT + ((c * LQ + lq) * OUTL + e) * 4);
          acc[c] += dot4(f4, w4);
        }
      }
      float xl = s.feat[row + 96];
      #pragma unroll
      for (int c = 0; c < NC; ++c) acc[c] += xl * capL[c * OUTL + e];
    } else {
      for (int c = 0; c < NC; ++c) {
        float a = 0.f;
        for (int l = 0; l < INL; ++l) a += s.feat[row + l] * Wcap[(c * OUTL + e) * INL + l];
        acc[c] = a;
      }
    }
    #pragma unroll
    for (int c = 0; c < NC; ++c) s.u.priors[PIDX(i, c) + e] = acc[c];
  }
  __syncthreads();

  if (tid < KP * NC) {
    int i = tid / NC, c = tid % NC;
    const float* pr = &s.u.priors[PIDX(i, c)];
    float a = 0.f;
    #pragma unroll
    for (int eq = 0; eq < 4; ++eq) { float4 p = ld4(pr + eq * 4); a += dot4(p, p); }
    s.v.r.prsq[tid] = a;
  }
  if (tid < NC * OUTL) {
    int c = tid >> 4, e = tid & 15;
    float a = 0.f;
    #pragma unroll
    for (int i = 0; i < KP; ++i) a += s.u.priors[PIDX(i, c) + e];
    s.v.r.outv[tid] = a * (1.0f / KP);
  }
  __syncthreads();

  for (int it = 0; it < NITER; ++it) {
    if (tid < KP * NC) {
      int i = tid / NC, c = tid % NC;
      const float* pr = &s.u.priors[PIDX(i, c)];
      const float* ov = &s.v.r.outv[c * OUTL];
      float xy = 0.f, oq = 0.f;
      #pragma unroll
      for (int eq = 0; eq < 4; ++eq) {
        float4 p = ld4(pr + eq * 4);
        float4 o = ld4(ov + eq * 4);
        xy += dot4(p, o); oq += dot4(o, o);
      }
      s.v.r.simbuf[tid] = xy / (s.v.r.prsq[tid] + oq - xy);
    }
    __syncthreads();
    if (tid < NC) {
      float m = -1e30f;
      #pragma unroll
      for (int i = 0; i < KP; ++i) m = fmaxf(m, s.v.r.simbuf[i * NC + tid]);
      float ss = 0.f;
      #pragma unroll
      for (int i = 0; i < KP; ++i) ss += __expf(s.v.r.simbuf[i * NC + tid] - m);
      s.v.r.smax[tid] = m;
      s.v.r.ssum[tid] = 1.f / ss;
    }
    __syncthreads();
    if (tid < NC * OUTL) {
      int c = tid >> 4, e = tid & 15;
      float m = s.v.r.smax[c], is = s.v.r.ssum[c], a = 0.f;
      #pragma unroll
      for (int i = 0; i < KP; ++i)
        a += __expf(s.v.r.simbuf[i * NC + c] - m) * s.u.priors[PIDX(i, c) + e];
      s.v.r.outv[tid] = a * is;
    }
    __syncthreads();
  }

  if (tid < NC) {
    const float* ov = &s.v.r.outv[tid * OUTL];
    float a = 0.f;
    #pragma unroll
    for (int eq = 0; eq < 4; ++eq) { float4 o = ld4(ov + eq * 4); a += dot4(o, o); }
    out[(size_t)g * NC + tid] = sqrtf(a);
  }
}

extern "C" void kernel_launch(void* const* d_in, const int* in_sizes, int n_in,
                              void* d_out, int out_size, void* d_ws, size_t ws_size,
                              hipStream_t stream) {
  const float* x    = (const float*)d_in[0];
  const int*   esrc = (const int*)d_in[1];
  const int*   edst = (const int*)d_in[2];
  const float* W1 = (const float*)d_in[4];
  const float* b1 = (const float*)d_in[5];
  const float* W2 = (const float*)d_in[6];
  const float* b2 = (const float*)d_in[7];
  const float* W3 = (const float*)d_in[8];
  const float* b3 = (const float*)d_in[9];
  const float* W4 = (const float*)d_in[10];
  const float* b4 = (const float*)d_in[11];
  const float* Wcap = (const float*)d_in[12];
  float* outp = (float*)d_out;

  const bool full = ws_size >= WS_FULL_BYTES;
  const bool wse  = ws_size >= WS_EDGES_BYTES + WS_CAP_BYTES;
  const bool wsc  = ws_size >= WS_CAP_BYTES;

  unsigned int* wsE = (unsigned int*)d_ws;
  float* capT = (full || wse) ? (float*)((char*)d_ws + WS_EDGES_BYTES) : (float*)d_ws;
  float* capL = capT + WS_CAPT_FLOATS;
  float* featG = (float*)((char*)d_ws + WS_FEATG_OFF);

  if (full) {
    (void)hipFuncSetAttribute((const void*)gcn_caps_v5,
                              hipFuncAttributeMaxDynamicSharedMemorySize, (int)sizeof(SMemV5));
    prek_edges<<<(EPG / 64) * 16, 256, 0, stream>>>(esrc, edst, wsE);
    prek_cap<<<(WS_CAPT_FLOATS + 255) / 256, 256, 0, stream>>>(Wcap, capT, capL);
    gcn_caps_v5<<<NGRAPH, NTV, sizeof(SMemV5), stream>>>(
        x, wsE, W1, b1, W2, b2, W3, b3, W4, b4, capT, capL, featG, outp);
  } else if (wse) {
    (void)hipFuncSetAttribute((const void*)gcn_caps_fused<true, true>,
                              hipFuncAttributeMaxDynamicSharedMemorySize, (int)sizeof(SMemF));
    prek_edges<<<(EPG / 64) * 16, 256, 0, stream>>>(esrc, edst, wsE);
    prek_cap<<<(WS_CAPT_FLOATS + 255) / 256, 256, 0, stream>>>(Wcap, capT, capL);
    gcn_caps_fused<true, true><<<NGRAPH, NTF, sizeof(SMemF), stream>>>(
        x, esrc, edst, W1, b1, W2, b2, W3, b3, W4, b4, Wcap, wsE, capT, capL, outp);
  } else if (wsc) {
    (void)hipFuncSetAttribute((const void*)gcn_caps_fused<false, true>,
                              hipFuncAttributeMaxDynamicSharedMemorySize, (int)sizeof(SMemF));
    prek_cap<<<(WS_CAPT_FLOATS + 255) / 256, 256, 0, stream>>>(Wcap, capT, capL);
    gcn_caps_fused<false, true><<<NGRAPH, NTF, sizeof(SMemF), stream>>>(
        x, esrc, edst, W1, b1, W2, b2, W3, b3, W4, b4, Wcap, wsE, capT, capL, outp);
  } else {
    (void)hipFuncSetAttribute((const void*)gcn_caps_fused<false, false>,
                              hipFuncAttributeMaxDynamicSharedMemorySize, (int)sizeof(SMemF));
    gcn_caps_fused<false, false><<<NGRAPH, NTF, sizeof(SMemF), stream>>>(
        x, esrc, edst, W1, b1, W2, b2, W3, b3, W4, b4, Wcap, wsE, capT, capL, outp);
  }
}